// Round 5
// baseline (486.218 us; speedup 1.0000x reference)
//
#include <hip/hip_runtime.h>
#include <math.h>

#define DIM 4096
#define NH 32
#define NKV 8
#define HD 128
#define B_ 8
#define SW 4096
#define PAD_LEN 2048
#define GQ 4                        // NH / NKV
#define QKV_COLS 6144               // DIM + 2*NKV*HD
#define KSQ 64                      // qkv split-K
#define KCQ 64                      // DIM / KSQ
#define KSO 128                     // oproj split-K
#define KCO 32                      // DIM / KSO
#define LCHUNK 64
#define NLCHUNK 32                  // PAD_LEN / LCHUNK
#define NTASK (64 * NLCHUNK)        // 2048 attn partial tasks
#define GRID2 512                   // attn persistent blocks (2/CU, all resident)
#define SCALE 0.08838834764831845f  // 1/sqrt(128)

// ---------------- workspace layout (float offsets) ----------------
#define OFF_QKVP   0                                        // KSQ*B_*QKV_COLS = 3145728
#define OFF_Q      (OFF_QKVP + KSQ * B_ * QKV_COLS)
#define OFF_K      (OFF_Q + B_ * DIM)
#define OFF_V      (OFF_K + B_ * NKV * HD)
#define OFF_AP     (OFF_V + B_ * NKV * HD)
#define OFF_AO     (OFF_AP + NTASK * GQ * (HD + 2))
#define OFF_OP     (OFF_AO + B_ * DIM)                      // KSO*B_*DIM
#define OFF_CTR    (OFF_OP + KSO * B_ * DIM)                // 16 uints

// device-scope atomic read (returns current value; atomicAdd on global is
// device-scope on CDNA)
__device__ __forceinline__ unsigned atomic_read(unsigned* p) {
    return atomicAdd(p, 0u);
}

// ---------------- kernel 1: qkv split-K + in-kernel reduce + RoPE ----------------
__global__ __launch_bounds__(256, 2)
void qkv_fused(const float* __restrict__ x,
               const float* __restrict__ wq,
               const float* __restrict__ wk,
               const float* __restrict__ wv,
               const float* __restrict__ rot,   // (B, HD, HD)
               float* __restrict__ part,
               float* __restrict__ qb,
               float* __restrict__ kb,
               float* __restrict__ vb,
               unsigned* __restrict__ ctr) {
    __shared__ float xs[B_][KCQ];
    __shared__ float4 red[32][8];
    const int tid = threadIdx.x;
    const int bx  = blockIdx.x;      // 0..5 column slice (4 wq, 1 wk, 1 wv)
    const int s   = blockIdx.y;      // 0..KSQ-1 split
    const int k0  = s * KCQ;

    if (tid < 128) {
        int r = tid >> 4, c4 = (tid & 15) * 4;
        *(float4*)&xs[r][c4] = *(const float4*)(x + r * DIM + k0 + c4);
    }
    __syncthreads();

    const float* W; int ldw, cbase;
    if (bx < 4)       { W = wq; ldw = NH * HD;  cbase = bx * 1024; }
    else if (bx == 4) { W = wk; ldw = NKV * HD; cbase = 0; }
    else              { W = wv; ldw = NKV * HD; cbase = 0; }
    const int c = cbase + tid * 4;

    float4 acc[B_];
    #pragma unroll
    for (int r = 0; r < B_; ++r) { acc[r].x = acc[r].y = acc[r].z = acc[r].w = 0.f; }

    const float* wp = W + (size_t)k0 * ldw + c;
    #pragma unroll 8
    for (int kk = 0; kk < KCQ; ++kk) {
        float4 w = *(const float4*)(wp + (size_t)kk * ldw);
        #pragma unroll
        for (int r = 0; r < B_; ++r) {
            float xv = xs[r][kk];
            acc[r].x = fmaf(xv, w.x, acc[r].x);
            acc[r].y = fmaf(xv, w.y, acc[r].y);
            acc[r].z = fmaf(xv, w.z, acc[r].z);
            acc[r].w = fmaf(xv, w.w, acc[r].w);
        }
    }
    const int colg = bx * 1024 + tid * 4;
    #pragma unroll
    for (int r = 0; r < B_; ++r)
        *(float4*)(part + (size_t)(s * B_ + r) * QKV_COLS + colg) = acc[r];

    // ---- device-scope release + arrive + wait for all splits of this slice ----
    __threadfence();
    __syncthreads();
    if (tid == 0) {
        atomicAdd(&ctr[bx], 1u);
        while (atomic_read(&ctr[bx]) < KSQ)
            __builtin_amdgcn_s_sleep(2);
    }
    __syncthreads();
    __threadfence();

    // ---- this block reduces cols [bx*1024 + s*16, +16) across all splits ----
    {
        const int combo = tid >> 3, sg = tid & 7;
        const int r = combo >> 2, c4i = combo & 3;
        const int col = bx * 1024 + s * 16 + c4i * 4;
        float4 v; v.x = v.y = v.z = v.w = 0.f;
        #pragma unroll
        for (int p2 = sg * 8; p2 < sg * 8 + 8; ++p2) {
            float4 t = *(const float4*)(part + (size_t)(p2 * B_ + r) * QKV_COLS + col);
            v.x += t.x; v.y += t.y; v.z += t.z; v.w += t.w;
        }
        red[combo][sg] = v;
    }
    __syncthreads();
    if (tid < 32) {
        const int r = tid >> 2, c4i = tid & 3;
        const int col = bx * 1024 + s * 16 + c4i * 4;
        float4 v; v.x = v.y = v.z = v.w = 0.f;
        #pragma unroll
        for (int j = 0; j < 8; ++j) {
            float4 t = red[tid][j];
            v.x += t.x; v.y += t.y; v.z += t.z; v.w += t.w;
        }
        if (bx < 5) {
            const int lc = (bx < 4) ? col : (col - DIM);
            const int hd = lc & (HD - 1);
            const float* rm = rot + (size_t)r * HD * HD;
            float c0 = rm[hd * HD + hd];
            float s0 = rm[(hd + 1) * HD + hd];
            float c1 = rm[(hd + 2) * HD + hd + 2];
            float s1 = rm[(hd + 3) * HD + hd + 2];
            float4 o;
            o.x = v.x * c0 + v.y * s0;
            o.y = v.y * c0 - v.x * s0;
            o.z = v.z * c1 + v.w * s1;
            o.w = v.w * c1 - v.z * s1;
            if (bx < 4) *(float4*)(qb + r * DIM + col) = o;
            else        *(float4*)(kb + r * NKV * HD + lc) = o;
        } else {
            *(float4*)(vb + r * NKV * HD + (col - DIM - NKV * HD)) = v;
        }
    }
}

// ---------------- kernel 2: attention partials + grid barrier + combine ----------------
__global__ __launch_bounds__(256, 2)
void attn_fused(const float* __restrict__ qb,
                const float* __restrict__ kb,
                const float* __restrict__ vb,
                const float* __restrict__ cache_k,
                const float* __restrict__ cache_v,
                const float* __restrict__ mask,     // (NH, B, PAD_LEN)
                const int* __restrict__ spp,
                float* __restrict__ part,
                float* __restrict__ attnout,
                unsigned* __restrict__ ctr) {       // ctr[0]=count, ctr[1]=gen
    __shared__ float k_lds[LCHUNK][HD + 4];
    __shared__ float q_lds[GQ][HD];
    __shared__ float p_lds[GQ][LCHUNK];
    const int tid  = threadIdx.x;
    const int lane = tid & 63;
    const int wave = tid >> 6;
    const int sp = spp[0];

    for (int t = blockIdx.x; t < NTASK; t += GRID2) {
        const int bg = t >> 5, chunk = t & 31;
        const int b = bg >> 3, g = bg & 7;
        const int l0 = chunk * LCHUNK;
        const size_t kvbase = (size_t)(b * NKV + g) * SW * HD;

        if (tid < 128) {
            int qh = tid >> 5, d4 = (tid & 31) * 4;
            *(float4*)&q_lds[qh][d4] = *(const float4*)(qb + b * DIM + (g * GQ + qh) * HD + d4);
        }
        const float* knp = kb + (b * NKV + g) * HD;
        #pragma unroll
        for (int i = 0; i < 8; ++i) {
            int idx = i * 256 + tid;
            int r = idx >> 5, c4 = (idx & 31) * 4;
            int lg = l0 + r;
            const float* src = (lg == sp) ? knp : (cache_k + kvbase + (size_t)lg * HD);
            *(float4*)&k_lds[r][c4] = *(const float4*)(src + c4);
        }
        __syncthreads();

        // QK^T: wave = query head, lane = key row
        float sc = 0.f;
        #pragma unroll 8
        for (int d = 0; d < HD; d += 4) {
            float4 kv = *(const float4*)&k_lds[lane][d];
            float4 qv = *(const float4*)&q_lds[wave][d];
            sc += kv.x * qv.x + kv.y * qv.y + kv.z * qv.z + kv.w * qv.w;
        }
        const int l = l0 + lane;
        float sv = sc * SCALE + mask[((size_t)(g * GQ + wave) * B_ + b) * PAD_LEN + l];
        float m = sv;
        #pragma unroll
        for (int off = 32; off > 0; off >>= 1)
            m = fmaxf(m, __shfl_xor(m, off, 64));
        float p = __expf(sv - m);
        float sum = p;
        #pragma unroll
        for (int off = 32; off > 0; off >>= 1)
            sum += __shfl_xor(sum, off, 64);
        p_lds[wave][lane] = p;
        __syncthreads();

        // stage V into the same LDS buffer
        const float* vnp = vb + (b * NKV + g) * HD;
        #pragma unroll
        for (int i = 0; i < 8; ++i) {
            int idx = i * 256 + tid;
            int r = idx >> 5, c4 = (idx & 31) * 4;
            int lg = l0 + r;
            const float* src = (lg == sp) ? vnp : (cache_v + kvbase + (size_t)lg * HD);
            *(float4*)&k_lds[r][c4] = *(const float4*)(src + c4);
        }
        __syncthreads();

        // PV: wave = query head, lane covers d via float2
        const int d2 = lane * 2;
        float2 acc; acc.x = 0.f; acc.y = 0.f;
        #pragma unroll 4
        for (int r = 0; r < LCHUNK; ++r) {
            float pp = p_lds[wave][r];
            float2 vv = *(const float2*)&k_lds[r][d2];
            acc.x = fmaf(pp, vv.x, acc.x);
            acc.y = fmaf(pp, vv.y, acc.y);
        }
        const size_t base = (size_t)t * GQ;
        *(float2*)(part + (base + wave) * (HD + 2) + 2 + d2) = acc;
        if (lane == 0) {
            part[(base + wave) * (HD + 2) + 0] = m;
            part[(base + wave) * (HD + 2) + 1] = sum;
        }
        __syncthreads();   // protect LDS before next task restages
    }

    // ---- grid barrier (all GRID2 blocks co-resident) ----
    __threadfence();
    __syncthreads();
    if (tid == 0) {
        unsigned gen = atomic_read(&ctr[1]);
        unsigned arr = atomicAdd(&ctr[0], 1u);
        if (arr == GRID2 - 1) {
            __threadfence();
            atomicAdd(&ctr[1], 1u);
        } else {
            while (atomic_read(&ctr[1]) == gen)
                __builtin_amdgcn_s_sleep(2);
        }
    }
    __syncthreads();
    __threadfence();

    // ---- combine: first 64 blocks, one (b,g) group each ----
    if (blockIdx.x < 64) {
        const int bg = blockIdx.x;
        const int b = bg >> 3, g = bg & 7;
        const int d = tid & 127;
        const int qh0 = (tid >> 7) * 2;
        for (int q = qh0; q < qh0 + 2; ++q) {
            float M = -3.4e38f;
            #pragma unroll 8
            for (int c2 = 0; c2 < NLCHUNK; ++c2)
                M = fmaxf(M, part[((size_t)(bg * NLCHUNK + c2) * GQ + q) * (HD + 2)]);
            float denom = 0.f, o = 0.f;
            #pragma unroll 8
            for (int c2 = 0; c2 < NLCHUNK; ++c2) {
                const float* pp = part + ((size_t)(bg * NLCHUNK + c2) * GQ + q) * (HD + 2);
                float w = __expf(pp[0] - M);
                denom += w * pp[1];
                o     += w * pp[2 + d];
            }
            attnout[b * DIM + (g * GQ + q) * HD + d] = o / denom;
        }
    }
}

// ---------------- kernel 3: output projection split-K + in-kernel reduce ----------------
__global__ __launch_bounds__(256, 2)
void oproj_fused(const float* __restrict__ xin,
                 const float* __restrict__ wo,
                 float* __restrict__ part,
                 float* __restrict__ out,
                 unsigned* __restrict__ ctr) {
    __shared__ float xs[B_][KCO];
    __shared__ float4 red[16][16];
    const int tid = threadIdx.x;
    const int bx  = blockIdx.x;      // 0..3 column slice
    const int s   = blockIdx.y;      // 0..KSO-1 split
    const int k0  = s * KCO;

    if (tid < 64) {
        int r = tid >> 3, c4 = (tid & 7) * 4;
        *(float4*)&xs[r][c4] = *(const float4*)(xin + r * DIM + k0 + c4);
    }
    __syncthreads();

    const int col = bx * 1024 + tid * 4;
    float4 acc[B_];
    #pragma unroll
    for (int r = 0; r < B_; ++r) { acc[r].x = acc[r].y = acc[r].z = acc[r].w = 0.f; }

    const float* wp = wo + (size_t)k0 * DIM + col;
    #pragma unroll 8
    for (int kk = 0; kk < KCO; ++kk) {
        float4 w = *(const float4*)(wp + (size_t)kk * DIM);
        #pragma unroll
        for (int r = 0; r < B_; ++r) {
            float xv = xs[r][kk];
            acc[r].x = fmaf(xv, w.x, acc[r].x);
            acc[r].y = fmaf(xv, w.y, acc[r].y);
            acc[r].z = fmaf(xv, w.z, acc[r].z);
            acc[r].w = fmaf(xv, w.w, acc[r].w);
        }
    }
    #pragma unroll
    for (int r = 0; r < B_; ++r)
        *(float4*)(part + (size_t)(s * B_ + r) * DIM + col) = acc[r];

    __threadfence();
    __syncthreads();
    if (tid == 0) {
        atomicAdd(&ctr[bx], 1u);
        while (atomic_read(&ctr[bx]) < KSO)
            __builtin_amdgcn_s_sleep(2);
    }
    __syncthreads();
    __threadfence();

    // reduce cols [bx*1024 + s*8, +8)
    {
        const int combo = tid >> 4, sg = tid & 15;
        const int r = combo >> 1, c4i = combo & 1;
        const int col2 = bx * 1024 + s * 8 + c4i * 4;
        float4 v; v.x = v.y = v.z = v.w = 0.f;
        #pragma unroll
        for (int p2 = sg * 8; p2 < sg * 8 + 8; ++p2) {
            float4 t = *(const float4*)(part + (size_t)(p2 * B_ + r) * DIM + col2);
            v.x += t.x; v.y += t.y; v.z += t.z; v.w += t.w;
        }
        red[combo][sg] = v;
    }
    __syncthreads();
    if (tid < 16) {
        const int r = tid >> 1, c4i = tid & 1;
        const int col2 = bx * 1024 + s * 8 + c4i * 4;
        float4 v; v.x = v.y = v.z = v.w = 0.f;
        #pragma unroll
        for (int j = 0; j < 16; ++j) {
            float4 t = red[tid][j];
            v.x += t.x; v.y += t.y; v.z += t.z; v.w += t.w;
        }
        *(float4*)(out + r * DIM + col2) = v;
    }
}

extern "C" void kernel_launch(void* const* d_in, const int* in_sizes, int n_in,
                              void* d_out, int out_size, void* d_ws, size_t ws_size,
                              hipStream_t stream) {
    const float* x        = (const float*)d_in[0];
    const float* wq       = (const float*)d_in[1];
    const float* wk       = (const float*)d_in[2];
    const float* wv       = (const float*)d_in[3];
    const float* wo       = (const float*)d_in[4];
    const float* rot      = (const float*)d_in[5];
    const float* cache_k  = (const float*)d_in[6];
    const float* cache_v  = (const float*)d_in[7];
    const float* mask     = (const float*)d_in[8];
    const int*   start_pp = (const int*)d_in[9];
    float* ws  = (float*)d_ws;
    float* out = (float*)d_out;
    unsigned* ctr = (unsigned*)(ws + OFF_CTR);

    (void)hipMemsetAsync(ctr, 0, 16 * sizeof(unsigned), stream);

    dim3 gA(6, KSQ);                       // 384 blocks, all co-resident
    qkv_fused<<<gA, 256, 0, stream>>>(x, wq, wk, wv, rot, ws + OFF_QKVP,
                                      ws + OFF_Q, ws + OFF_K, ws + OFF_V, ctr);

    attn_fused<<<dim3(GRID2), 256, 0, stream>>>(ws + OFF_Q, ws + OFF_K, ws + OFF_V,
                                                cache_k, cache_v, mask, start_pp,
                                                ws + OFF_AP, ws + OFF_AO, ctr + 6);

    dim3 gD(4, KSO);                       // 512 blocks, all co-resident
    oproj_fused<<<gD, 256, 0, stream>>>(ws + OFF_AO, wo, ws + OFF_OP, out, ctr + 8);
}

// Round 6
// 220.281 us; speedup vs baseline: 2.2073x; 2.2073x over previous
//
#include <hip/hip_runtime.h>
#include <math.h>

#define DIM 4096
#define NH 32
#define NKV 8
#define HD 128
#define B_ 8
#define SW 4096
#define PAD_LEN 2048
#define GQ 4                        // NH / NKV
#define QKVC 6144                   // DIM + 2*NKV*HD
#define KSQ 128                     // qkv split-K
#define KCQ 32                      // DIM / KSQ
#define KSO 128                     // oproj split-K
#define KCO 32                      // DIM / KSO
#define LCHUNK 64
#define NLCHUNK 32                  // PAD_LEN / LCHUNK
#define SCALE 0.08838834764831845f  // 1/sqrt(128)

// ---------------- workspace layout (float offsets) ----------------
#define OFF_RAW 0                            // B_*QKVC = 49152 (pre-rope q,k,v)
#define OFF_AP  (OFF_RAW + B_ * QKVC)        // 64*32*GQ*(HD+2) = 1064960

// ---------------- kernel 1: qkv projection, split-K, atomic accumulate ----------------
__global__ __launch_bounds__(256)
void qkv_gemm(const float* __restrict__ x,
              const float* __restrict__ wq,
              const float* __restrict__ wk,
              const float* __restrict__ wv,
              float* __restrict__ raw) {
    __shared__ float xs[B_][KCQ];
    const int tid = threadIdx.x;
    const int bx  = blockIdx.x;      // 0..5: 4 wq slices, 1 wk, 1 wv
    const int k0  = blockIdx.y * KCQ;

    if (tid < 64) {
        int r = tid >> 3, c4 = (tid & 7) * 4;
        *(float4*)&xs[r][c4] = *(const float4*)(x + r * DIM + k0 + c4);
    }
    __syncthreads();

    const float* W; int ldw, cbase;
    if (bx < 4)       { W = wq; ldw = NH * HD;  cbase = bx * 1024; }
    else if (bx == 4) { W = wk; ldw = NKV * HD; cbase = 0; }
    else              { W = wv; ldw = NKV * HD; cbase = 0; }
    const int c = cbase + tid * 4;

    float4 acc[B_];
    #pragma unroll
    for (int r = 0; r < B_; ++r) { acc[r].x = acc[r].y = acc[r].z = acc[r].w = 0.f; }

    const float* wp = W + (size_t)k0 * ldw + c;
    #pragma unroll 16
    for (int kk = 0; kk < KCQ; ++kk) {
        float4 w = *(const float4*)(wp + (size_t)kk * ldw);
        #pragma unroll
        for (int r = 0; r < B_; ++r) {
            float xv = xs[r][kk];
            acc[r].x = fmaf(xv, w.x, acc[r].x);
            acc[r].y = fmaf(xv, w.y, acc[r].y);
            acc[r].z = fmaf(xv, w.z, acc[r].z);
            acc[r].w = fmaf(xv, w.w, acc[r].w);
        }
    }
    const int colg = bx * 1024 + tid * 4;
    #pragma unroll
    for (int r = 0; r < B_; ++r) {
        float* p = raw + (size_t)r * QKVC + colg;
        atomicAdd(p + 0, acc[r].x);
        atomicAdd(p + 1, acc[r].y);
        atomicAdd(p + 2, acc[r].z);
        atomicAdd(p + 3, acc[r].w);
    }
}

// ---------------- kernel 2: attention partials (RoPE on the fly) ----------------
__global__ __launch_bounds__(256)
void attn_partial(const float* __restrict__ raw,
                  const float* __restrict__ rot,      // (B, HD, HD)
                  const float* __restrict__ cache_k,
                  const float* __restrict__ cache_v,
                  const float* __restrict__ mask,     // (NH, B, PAD_LEN)
                  const int* __restrict__ spp,
                  float* __restrict__ part) {
    const int bg = blockIdx.x;          // 0..63
    const int b  = bg >> 3;
    const int g  = bg & 7;
    const int chunk = blockIdx.y;       // 0..NLCHUNK-1
    const int l0 = chunk * LCHUNK;
    const int tid  = threadIdx.x;
    const int lane = tid & 63;
    const int wave = tid >> 6;
    const int sp = spp[0];

    __shared__ float k_lds[LCHUNK][HD + 4];
    __shared__ float q_lds[GQ][HD];
    __shared__ float p_lds[GQ][LCHUNK];

    const float* rm = rot + (size_t)b * HD * HD;

    // q: load raw + apply rope
    if (tid < 128) {
        int qh = tid >> 5, d4 = (tid & 31) * 4;
        float4 v = *(const float4*)(raw + (size_t)b * QKVC + (g * GQ + qh) * HD + d4);
        float c0 = rm[d4 * HD + d4];
        float s0 = rm[(d4 + 1) * HD + d4];
        float c1 = rm[(d4 + 2) * HD + d4 + 2];
        float s1 = rm[(d4 + 3) * HD + d4 + 2];
        float4 o;
        o.x = v.x * c0 + v.y * s0;
        o.y = v.y * c0 - v.x * s0;
        o.z = v.z * c1 + v.w * s1;
        o.w = v.w * c1 - v.z * s1;
        *(float4*)&q_lds[qh][d4] = o;
    }
    // stage K chunk (rope the new row at sp)
    const size_t kvbase = (size_t)(b * NKV + g) * SW * HD;
    #pragma unroll
    for (int i = 0; i < 8; ++i) {
        int idx = i * 256 + tid;
        int r = idx >> 5, c4 = (idx & 31) * 4;
        int lg = l0 + r;
        float4 kv;
        if (lg == sp) {
            float4 v = *(const float4*)(raw + (size_t)b * QKVC + DIM + g * HD + c4);
            float c0 = rm[c4 * HD + c4];
            float s0 = rm[(c4 + 1) * HD + c4];
            float c1 = rm[(c4 + 2) * HD + c4 + 2];
            float s1 = rm[(c4 + 3) * HD + c4 + 2];
            kv.x = v.x * c0 + v.y * s0;
            kv.y = v.y * c0 - v.x * s0;
            kv.z = v.z * c1 + v.w * s1;
            kv.w = v.w * c1 - v.z * s1;
        } else {
            kv = *(const float4*)(cache_k + kvbase + (size_t)lg * HD + c4);
        }
        *(float4*)&k_lds[r][c4] = kv;
    }
    __syncthreads();

    // QK^T: wave = query head, lane = key row
    float sc = 0.f;
    #pragma unroll 8
    for (int d = 0; d < HD; d += 4) {
        float4 kv = *(const float4*)&k_lds[lane][d];
        float4 qv = *(const float4*)&q_lds[wave][d];
        sc += kv.x * qv.x + kv.y * qv.y + kv.z * qv.z + kv.w * qv.w;
    }
    const int l = l0 + lane;
    float sv = sc * SCALE + mask[((size_t)(g * GQ + wave) * B_ + b) * PAD_LEN + l];
    float m = sv;
    #pragma unroll
    for (int off = 32; off > 0; off >>= 1)
        m = fmaxf(m, __shfl_xor(m, off, 64));
    float p = __expf(sv - m);
    float sum = p;
    #pragma unroll
    for (int off = 32; off > 0; off >>= 1)
        sum += __shfl_xor(sum, off, 64);
    p_lds[wave][lane] = p;
    __syncthreads();

    // stage V into the same LDS buffer
    #pragma unroll
    for (int i = 0; i < 8; ++i) {
        int idx = i * 256 + tid;
        int r = idx >> 5, c4 = (idx & 31) * 4;
        int lg = l0 + r;
        const float* src = (lg == sp) ? (raw + (size_t)b * QKVC + DIM + NKV * HD + g * HD)
                                      : (cache_v + kvbase + (size_t)lg * HD);
        *(float4*)&k_lds[r][c4] = *(const float4*)(src + c4);
    }
    __syncthreads();

    // PV: wave = query head, lane covers d via float2
    const int d2 = lane * 2;
    float2 acc; acc.x = 0.f; acc.y = 0.f;
    #pragma unroll 4
    for (int r = 0; r < LCHUNK; ++r) {
        float pp = p_lds[wave][r];
        float2 vv = *(const float2*)&k_lds[r][d2];
        acc.x = fmaf(pp, vv.x, acc.x);
        acc.y = fmaf(pp, vv.y, acc.y);
    }
    const size_t base = ((size_t)bg * NLCHUNK + chunk) * GQ;
    *(float2*)(part + (base + wave) * (HD + 2) + 2 + d2) = acc;
    if (lane == 0) {
        part[(base + wave) * (HD + 2) + 0] = m;
        part[(base + wave) * (HD + 2) + 1] = sum;
    }
}

// ---------------- kernel 3: combine-on-read + output projection, atomic accumulate ----------------
__global__ __launch_bounds__(256)
void oproj_gemm(const float* __restrict__ part,
                const float* __restrict__ wo,
                float* __restrict__ out) {
    __shared__ float xs[B_][KCO];
    const int tid = threadIdx.x;
    const int bx  = blockIdx.x;      // 0..3 column slice
    const int s   = blockIdx.y;      // 0..KSO-1 split
    const int k0  = s * KCO;
    const int h   = s >> 2;          // head this k-slice belongs to
    const int g   = h >> 2;
    const int qh  = h & 3;
    const int dbase = (s & 3) * 32;

    // combine-on-read: thread (r, kk) reconstructs attnout[r][k0+kk]
    {
        const int r  = tid >> 5;
        const int kk = tid & 31;
        const int d  = dbase + kk;
        const size_t eb = ((size_t)(r * NKV + g) * NLCHUNK) * GQ + qh;
        float M = -3.4e38f;
        #pragma unroll 8
        for (int c = 0; c < NLCHUNK; ++c)
            M = fmaxf(M, part[(eb + (size_t)c * GQ) * (HD + 2)]);
        float den = 0.f, o = 0.f;
        #pragma unroll 8
        for (int c = 0; c < NLCHUNK; ++c) {
            const float* pp = part + (eb + (size_t)c * GQ) * (HD + 2);
            float w = __expf(pp[0] - M);
            den += w * pp[1];
            o   += w * pp[2 + d];
        }
        xs[r][kk] = o / den;
    }
    __syncthreads();

    const int col = bx * 1024 + tid * 4;
    float4 acc[B_];
    #pragma unroll
    for (int r = 0; r < B_; ++r) { acc[r].x = acc[r].y = acc[r].z = acc[r].w = 0.f; }

    const float* wp = wo + (size_t)k0 * DIM + col;
    #pragma unroll 16
    for (int kk = 0; kk < KCO; ++kk) {
        float4 w = *(const float4*)(wp + (size_t)kk * DIM);
        #pragma unroll
        for (int r = 0; r < B_; ++r) {
            float xv = xs[r][kk];
            acc[r].x = fmaf(xv, w.x, acc[r].x);
            acc[r].y = fmaf(xv, w.y, acc[r].y);
            acc[r].z = fmaf(xv, w.z, acc[r].z);
            acc[r].w = fmaf(xv, w.w, acc[r].w);
        }
    }
    #pragma unroll
    for (int r = 0; r < B_; ++r) {
        float* p = out + (size_t)r * DIM + col;
        atomicAdd(p + 0, acc[r].x);
        atomicAdd(p + 1, acc[r].y);
        atomicAdd(p + 2, acc[r].z);
        atomicAdd(p + 3, acc[r].w);
    }
}

extern "C" void kernel_launch(void* const* d_in, const int* in_sizes, int n_in,
                              void* d_out, int out_size, void* d_ws, size_t ws_size,
                              hipStream_t stream) {
    const float* x        = (const float*)d_in[0];
    const float* wq       = (const float*)d_in[1];
    const float* wk       = (const float*)d_in[2];
    const float* wv       = (const float*)d_in[3];
    const float* wo       = (const float*)d_in[4];
    const float* rot      = (const float*)d_in[5];
    const float* cache_k  = (const float*)d_in[6];
    const float* cache_v  = (const float*)d_in[7];
    const float* mask     = (const float*)d_in[8];
    const int*   start_pp = (const int*)d_in[9];
    float* ws  = (float*)d_ws;
    float* out = (float*)d_out;

    // zero the atomic-accumulation targets (in-stream, graph-safe)
    (void)hipMemsetAsync(ws + OFF_RAW, 0, B_ * QKVC * sizeof(float), stream);
    (void)hipMemsetAsync(out, 0, (size_t)out_size * sizeof(float), stream);

    dim3 gA(6, KSQ);                        // 768 blocks
    qkv_gemm<<<gA, 256, 0, stream>>>(x, wq, wk, wv, ws + OFF_RAW);

    dim3 gB(64, NLCHUNK);                   // 2048 blocks
    attn_partial<<<gB, 256, 0, stream>>>(ws + OFF_RAW, rot, cache_k, cache_v,
                                         mask, start_pp, ws + OFF_AP);

    dim3 gC(4, KSO);                        // 512 blocks
    oproj_gemm<<<gC, 256, 0, stream>>>(ws + OFF_AP, wo, out);
}